// Round 1
// baseline (2209.032 us; speedup 1.0000x reference)
//
#include <hip/hip_runtime.h>
#include <hip/hip_bf16.h>

constexpr int NN = 100000;
constexpr int NE = 625000;
constexpr int F  = 128;
constexpr int C  = 32;
constexpr int CH = F / 4;   // float4 chunks per row = 32

// deg = 1 (self loop)
__global__ void k_deg_init(float* __restrict__ deg) {
    int i = blockIdx.x * blockDim.x + threadIdx.x;
    if (i < NN) deg[i] = 1.0f;
}

// deg[dst[e]] += 1
__global__ void k_deg_edges(const int* __restrict__ dstA, float* __restrict__ deg) {
    int e = blockIdx.x * blockDim.x + threadIdx.x;
    if (e < NE) atomicAdd(&deg[dstA[e]], 1.0f);
}

// dinv = rsqrt(deg)   (deg >= 1 always, so no zero-guard needed)
__global__ void k_dinv(float* __restrict__ deg) {
    int i = blockIdx.x * blockDim.x + threadIdx.x;
    if (i < NN) deg[i] = rsqrtf(deg[i]);
}

// y[i] = dinv[i]^2 * x[i]   (self-loop contribution; also zero-inits y)
__global__ void k_selfinit(const float* __restrict__ x, const float* __restrict__ dinv,
                           float* __restrict__ y) {
    int t = blockIdx.x * blockDim.x + threadIdx.x;   // one float4 per thread
    if (t >= NN * CH) return;
    int node = t / CH;
    float d = dinv[node];
    float c = d * d;
    float4 v = ((const float4*)x)[t];
    ((float4*)y)[t] = make_float4(c * v.x, c * v.y, c * v.z, c * v.w);
}

// y[dst] += dinv[src]*dinv[dst] * x[src]  — thread per (edge, float4-chunk)
__global__ void k_scatter(const float* __restrict__ x, const int* __restrict__ srcA,
                          const int* __restrict__ dstA, const float* __restrict__ dinv,
                          float* __restrict__ y) {
    long t = (long)blockIdx.x * blockDim.x + threadIdx.x;
    if (t >= (long)NE * CH) return;
    int e = (int)(t >> 5);          // CH = 32
    int q = (int)(t & 31);
    int s = srcA[e];
    int d = dstA[e];
    float c = dinv[s] * dinv[d];
    float4 v = ((const float4*)x)[s * CH + q];
    float* yp = y + (long)d * F + q * 4;
    atomicAdd(yp + 0, c * v.x);
    atomicAdd(yp + 1, c * v.y);
    atomicAdd(yp + 2, c * v.z);
    atomicAdd(yp + 3, c * v.w);
}

// logits = x @ W^T + b ; out = log_softmax(logits)
__global__ __launch_bounds__(256) void k_head(const float* __restrict__ x,
                                              const float* __restrict__ W,
                                              const float* __restrict__ b,
                                              float* __restrict__ out) {
    __shared__ float Ws[C * F];
    __shared__ float bs[C];
    for (int i = threadIdx.x; i < C * F; i += 256) Ws[i] = W[i];
    if (threadIdx.x < C) bs[threadIdx.x] = b[threadIdx.x];
    __syncthreads();

    int node = blockIdx.x * blockDim.x + threadIdx.x;
    if (node >= NN) return;

    float acc[C];
    #pragma unroll
    for (int c = 0; c < C; ++c) acc[c] = bs[c];

    const float4* xr = (const float4*)(x + (long)node * F);
    #pragma unroll 4
    for (int q = 0; q < CH; ++q) {
        float4 xv = xr[q];
        #pragma unroll
        for (int c = 0; c < C; ++c) {
            float4 wv = ((const float4*)Ws)[c * CH + q];   // wave-uniform -> LDS broadcast
            acc[c] += xv.x * wv.x + xv.y * wv.y + xv.z * wv.z + xv.w * wv.w;
        }
    }

    float m = acc[0];
    #pragma unroll
    for (int c = 1; c < C; ++c) m = fmaxf(m, acc[c]);
    float s = 0.f;
    #pragma unroll
    for (int c = 0; c < C; ++c) s += expf(acc[c] - m);
    float lse = m + logf(s);

    float4* op = (float4*)(out + (long)node * C);
    #pragma unroll
    for (int q = 0; q < C / 4; ++q) {
        float4 r;
        r.x = acc[q * 4 + 0] - lse;
        r.y = acc[q * 4 + 1] - lse;
        r.z = acc[q * 4 + 2] - lse;
        r.w = acc[q * 4 + 3] - lse;
        op[q] = r;
    }
}

extern "C" void kernel_launch(void* const* d_in, const int* in_sizes, int n_in,
                              void* d_out, int out_size, void* d_ws, size_t ws_size,
                              hipStream_t stream) {
    const float* x = (const float*)d_in[0];
    const int*   ei = (const int*)d_in[1];     // [2, NE] int32 (JAX x64 disabled)
    const float* W = (const float*)d_in[2];
    const float* b = (const float*)d_in[3];
    float* out = (float*)d_out;

    float* ws   = (float*)d_ws;
    float* dinv = ws;                          // NN floats (padded region 128K floats)
    float* y0   = ws + (1 << 17);
    float* y1   = y0 + (size_t)NN * F;

    const int* srcA = ei;                      // edge_index[0]
    const int* dstA = ei + NE;                 // edge_index[1]

    k_deg_init<<<(NN + 255) / 256, 256, 0, stream>>>(dinv);
    k_deg_edges<<<(NE + 255) / 256, 256, 0, stream>>>(dstA, dinv);
    k_dinv<<<(NN + 255) / 256, 256, 0, stream>>>(dinv);

    int scatter_blocks = (int)(((long)NE * CH + 255) / 256);   // 78125
    // hop 1: x -> y0
    k_selfinit<<<(NN * CH + 255) / 256, 256, 0, stream>>>(x, dinv, y0);
    k_scatter<<<scatter_blocks, 256, 0, stream>>>(x, srcA, dstA, dinv, y0);
    // hop 2: y0 -> y1
    k_selfinit<<<(NN * CH + 255) / 256, 256, 0, stream>>>(y0, dinv, y1);
    k_scatter<<<scatter_blocks, 256, 0, stream>>>(y0, srcA, dstA, dinv, y1);

    k_head<<<(NN + 255) / 256, 256, 0, stream>>>(y1, W, b, out);
}

// Round 2
// 422.183 us; speedup vs baseline: 5.2324x; 5.2324x over previous
//
#include <hip/hip_runtime.h>
#include <hip/hip_bf16.h>

constexpr int NN = 100000;
constexpr int NE = 625000;
constexpr int F  = 128;
constexpr int C  = 32;
constexpr int CH  = F / 4;  // 32 float4 per input row
constexpr int CQ  = C / 4;  // 8 float4 per projected row

// ---------- degree / norm ----------
__global__ void k_zero(int* __restrict__ cnt) {
    int i = blockIdx.x * blockDim.x + threadIdx.x;
    if (i < NN) cnt[i] = 0;
}

__global__ void k_count(const int* __restrict__ dstA, int* __restrict__ cnt) {
    int e = blockIdx.x * blockDim.x + threadIdx.x;
    if (e < NE) atomicAdd(&cnt[dstA[e]], 1);
}

__global__ void k_dinv(const int* __restrict__ cnt, float* __restrict__ dinv) {
    int i = blockIdx.x * blockDim.x + threadIdx.x;
    if (i < NN) dinv[i] = rsqrtf((float)(cnt[i] + 1));   // +1 self loop
}

// ---------- CSR build ----------
// single-workgroup scan: rowptr = exclusive_scan(cnt); cursor = copy of rowptr
__global__ __launch_bounds__(1024) void k_scan(const int* __restrict__ cnt,
                                               int* __restrict__ rowptr,
                                               int* __restrict__ cursor) {
    __shared__ int sums[1024];
    const int PER = (NN + 1023) / 1024;   // 98
    int t = threadIdx.x;
    int base = t * PER;
    int s = 0;
    for (int i = 0; i < PER; ++i) {
        int idx = base + i;
        if (idx < NN) s += cnt[idx];
    }
    sums[t] = s;
    __syncthreads();
    for (int off = 1; off < 1024; off <<= 1) {     // Hillis-Steele inclusive scan
        int v = (t >= off) ? sums[t - off] : 0;
        __syncthreads();
        sums[t] += v;
        __syncthreads();
    }
    int run = (t == 0) ? 0 : sums[t - 1];
    for (int i = 0; i < PER; ++i) {
        int idx = base + i;
        if (idx < NN) {
            rowptr[idx] = run;
            cursor[idx] = run;
            run += cnt[idx];
        }
    }
    if (t == 1023) rowptr[NN] = run;   // == NE (tail thread's elems all OOB, run = total)
}

__global__ void k_fill(const int* __restrict__ srcA, const int* __restrict__ dstA,
                       const float* __restrict__ dinv, int* __restrict__ cursor,
                       int* __restrict__ col, float* __restrict__ wgt) {
    int e = blockIdx.x * blockDim.x + threadIdx.x;
    if (e >= NE) return;
    int s = srcA[e], d = dstA[e];
    int pos = atomicAdd(&cursor[d], 1);
    col[pos] = s;
    wgt[pos] = dinv[s] * dinv[d];
}

// ---------- projection: z = x @ W^T  (bias deferred to the end) ----------
__global__ __launch_bounds__(256) void k_proj(const float* __restrict__ x,
                                              const float* __restrict__ W,
                                              float* __restrict__ z) {
    __shared__ float Ws[C * F];
    for (int i = threadIdx.x; i < C * F; i += 256) Ws[i] = W[i];
    __syncthreads();

    int node = blockIdx.x * blockDim.x + threadIdx.x;
    if (node >= NN) return;

    float acc[C];
    #pragma unroll
    for (int c = 0; c < C; ++c) acc[c] = 0.f;

    const float4* xr = (const float4*)(x + (long)node * F);
    #pragma unroll 4
    for (int q = 0; q < CH; ++q) {
        float4 xv = xr[q];
        #pragma unroll
        for (int c = 0; c < C; ++c) {
            float4 wv = ((const float4*)Ws)[c * CH + q];   // wave-uniform -> LDS broadcast
            acc[c] += xv.x * wv.x + xv.y * wv.y + xv.z * wv.z + xv.w * wv.w;
        }
    }
    float4* zp = (float4*)(z + (long)node * C);
    #pragma unroll
    for (int q = 0; q < CQ; ++q)
        zp[q] = make_float4(acc[q*4+0], acc[q*4+1], acc[q*4+2], acc[q*4+3]);
}

// ---------- propagation hop (gather): zout[i] = dinv[i]^2*zin[i] + sum_e w*zin[col] ----------
__global__ void k_gather(const float* __restrict__ zin, const int* __restrict__ rowptr,
                         const int* __restrict__ col, const float* __restrict__ wgt,
                         const float* __restrict__ dinv, float* __restrict__ zout) {
    int t = blockIdx.x * blockDim.x + threadIdx.x;   // thread per (node, float4 chunk)
    if (t >= NN * CQ) return;
    int node = t >> 3;   // CQ = 8
    int q    = t & 7;
    float dn = dinv[node];
    float4 v = ((const float4*)zin)[node * CQ + q];
    float c  = dn * dn;
    float ax = c * v.x, ay = c * v.y, az = c * v.z, aw = c * v.w;
    int e0 = rowptr[node], e1 = rowptr[node + 1];
    for (int e = e0; e < e1; ++e) {
        int   s = col[e];
        float w = wgt[e];
        float4 u = ((const float4*)zin)[s * CQ + q];
        ax += w * u.x; ay += w * u.y; az += w * u.z; aw += w * u.w;
    }
    ((float4*)zout)[node * CQ + q] = make_float4(ax, ay, az, aw);
}

// ---------- epilogue: out = log_softmax(z + b) ----------
__global__ void k_finish(const float* __restrict__ z, const float* __restrict__ b,
                         float* __restrict__ out) {
    int node = blockIdx.x * blockDim.x + threadIdx.x;
    if (node >= NN) return;
    float v[C];
    const float4* zp = (const float4*)(z + (long)node * C);
    #pragma unroll
    for (int q = 0; q < CQ; ++q) {
        float4 t = zp[q];
        v[q*4+0] = t.x + b[q*4+0];
        v[q*4+1] = t.y + b[q*4+1];
        v[q*4+2] = t.z + b[q*4+2];
        v[q*4+3] = t.w + b[q*4+3];
    }
    float m = v[0];
    #pragma unroll
    for (int c = 1; c < C; ++c) m = fmaxf(m, v[c]);
    float s = 0.f;
    #pragma unroll
    for (int c = 0; c < C; ++c) s += expf(v[c] - m);
    float lse = m + logf(s);
    float4* op = (float4*)(out + (long)node * C);
    #pragma unroll
    for (int q = 0; q < CQ; ++q)
        op[q] = make_float4(v[q*4+0]-lse, v[q*4+1]-lse, v[q*4+2]-lse, v[q*4+3]-lse);
}

extern "C" void kernel_launch(void* const* d_in, const int* in_sizes, int n_in,
                              void* d_out, int out_size, void* d_ws, size_t ws_size,
                              hipStream_t stream) {
    const float* x  = (const float*)d_in[0];
    const int*   ei = (const int*)d_in[1];     // [2, NE] int32
    const float* W  = (const float*)d_in[2];
    const float* b  = (const float*)d_in[3];
    float* out = (float*)d_out;

    const int* srcA = ei;
    const int* dstA = ei + NE;

    // workspace layout (bytes, 256-aligned blocks)
    char* p = (char*)d_ws;
    auto alloc = [&](size_t bytes) { char* r = p; p += (bytes + 255) & ~(size_t)255; return r; };
    int*   cnt    = (int*)  alloc(sizeof(int) * NN);
    float* dinv   = (float*)alloc(sizeof(float) * NN);
    int*   rowptr = (int*)  alloc(sizeof(int) * (NN + 1));
    int*   cursor = (int*)  alloc(sizeof(int) * NN);
    int*   col    = (int*)  alloc(sizeof(int) * NE);
    float* wgt    = (float*)alloc(sizeof(float) * NE);
    float* z0     = (float*)alloc(sizeof(float) * (size_t)NN * C);
    float* z1     = (float*)alloc(sizeof(float) * (size_t)NN * C);
    float* z2     = z0;   // hop2 output reuses z0 (z0 dead after hop2 reads... hop2 reads z1)

    // norm + CSR build
    k_zero <<<(NN + 255) / 256, 256, 0, stream>>>(cnt);
    k_count<<<(NE + 255) / 256, 256, 0, stream>>>(dstA, cnt);
    k_dinv <<<(NN + 255) / 256, 256, 0, stream>>>(cnt, dinv);
    k_scan <<<1, 1024, 0, stream>>>(cnt, rowptr, cursor);
    k_fill <<<(NE + 255) / 256, 256, 0, stream>>>(srcA, dstA, dinv, cursor, col, wgt);

    // project first (propagation commutes with the linear head)
    k_proj<<<(NN + 255) / 256, 256, 0, stream>>>(x, W, z0);

    // two hops on 32 features
    int gthreads = NN * CQ;
    k_gather<<<(gthreads + 255) / 256, 256, 0, stream>>>(z0, rowptr, col, wgt, dinv, z1);
    k_gather<<<(gthreads + 255) / 256, 256, 0, stream>>>(z1, rowptr, col, wgt, dinv, z2);

    // bias + log_softmax
    k_finish<<<(NN + 255) / 256, 256, 0, stream>>>(z2, b, out);
}

// Round 3
// 171.609 us; speedup vs baseline: 12.8725x; 2.4601x over previous
//
#include <hip/hip_runtime.h>
#include <hip/hip_bf16.h>

constexpr int NN = 100000;
constexpr int NE = 625000;
constexpr int F  = 128;
constexpr int C  = 32;
constexpr int CH  = F / 4;  // 32 float4 per input row
constexpr int CQ  = C / 4;  // 8 float4 per projected row
constexpr int NB  = (NN + 255) / 256;   // 391 scan blocks

// ---------- degree / norm ----------
__global__ void k_zero(int* __restrict__ cnt) {
    int i = blockIdx.x * blockDim.x + threadIdx.x;
    if (i < NN) cnt[i] = 0;
}

__global__ void k_count(const int* __restrict__ dstA, int* __restrict__ cnt) {
    int e = blockIdx.x * blockDim.x + threadIdx.x;
    if (e < NE) atomicAdd(&cnt[dstA[e]], 1);
}

__global__ void k_dinv(const int* __restrict__ cnt, float* __restrict__ dinv) {
    int i = blockIdx.x * blockDim.x + threadIdx.x;
    if (i < NN) dinv[i] = rsqrtf((float)(cnt[i] + 1));   // +1 self loop
}

// ---------- CSR build: two-level scan ----------
// A: per-block (256-elem chunk) reduction of cnt -> blocksums
__global__ __launch_bounds__(256) void k_blocksum(const int* __restrict__ cnt,
                                                  int* __restrict__ blocksums) {
    int idx = blockIdx.x * 256 + threadIdx.x;
    int v = (idx < NN) ? cnt[idx] : 0;
    // wave64 reduce
    #pragma unroll
    for (int off = 32; off; off >>= 1) v += __shfl_down(v, off, 64);
    __shared__ int ws[4];
    int lane = threadIdx.x & 63, wid = threadIdx.x >> 6;
    if (lane == 0) ws[wid] = v;
    __syncthreads();
    if (threadIdx.x == 0)
        blocksums[blockIdx.x] = ws[0] + ws[1] + ws[2] + ws[3];
}

// B: single-block exclusive scan of the 391 blocksums -> blockoff; rowptr[NN]=total
__global__ __launch_bounds__(512) void k_scanB(const int* __restrict__ blocksums,
                                               int* __restrict__ blockoff,
                                               int* __restrict__ rowptr) {
    __shared__ int s[512];
    int t = threadIdx.x;
    s[t] = (t < NB) ? blocksums[t] : 0;
    __syncthreads();
    for (int off = 1; off < 512; off <<= 1) {     // Hillis-Steele inclusive
        int v = (t >= off) ? s[t - off] : 0;
        __syncthreads();
        s[t] += v;
        __syncthreads();
    }
    if (t < NB) blockoff[t] = (t == 0) ? 0 : s[t - 1];
    if (t == NB - 1) rowptr[NN] = s[t];
}

// C: per-block local exclusive scan + block offset -> rowptr, cursor
__global__ __launch_bounds__(256) void k_scanC(const int* __restrict__ cnt,
                                               const int* __restrict__ blockoff,
                                               int* __restrict__ rowptr,
                                               int* __restrict__ cursor) {
    __shared__ int s[256];
    int t = threadIdx.x;
    int idx = blockIdx.x * 256 + t;
    int val = (idx < NN) ? cnt[idx] : 0;
    s[t] = val;
    __syncthreads();
    for (int off = 1; off < 256; off <<= 1) {     // inclusive
        int v = (t >= off) ? s[t - off] : 0;
        __syncthreads();
        s[t] += v;
        __syncthreads();
    }
    if (idx < NN) {
        int r = blockoff[blockIdx.x] + s[t] - val;   // exclusive
        rowptr[idx] = r;
        cursor[idx] = r;
    }
}

__global__ void k_fill(const int* __restrict__ srcA, const int* __restrict__ dstA,
                       const float* __restrict__ dinv, int* __restrict__ cursor,
                       int* __restrict__ col, float* __restrict__ wgt) {
    int e = blockIdx.x * blockDim.x + threadIdx.x;
    if (e >= NE) return;
    int s = srcA[e], d = dstA[e];
    int pos = atomicAdd(&cursor[d], 1);
    col[pos] = s;
    wgt[pos] = dinv[s] * dinv[d];
}

// ---------- projection: z = x @ W^T  (bias deferred to the end) ----------
__global__ __launch_bounds__(256) void k_proj(const float* __restrict__ x,
                                              const float* __restrict__ W,
                                              float* __restrict__ z) {
    __shared__ float Ws[C * F];
    for (int i = threadIdx.x; i < C * F; i += 256) Ws[i] = W[i];
    __syncthreads();

    int node = blockIdx.x * blockDim.x + threadIdx.x;
    if (node >= NN) return;

    float acc[C];
    #pragma unroll
    for (int c = 0; c < C; ++c) acc[c] = 0.f;

    const float4* xr = (const float4*)(x + (long)node * F);
    #pragma unroll 4
    for (int q = 0; q < CH; ++q) {
        float4 xv = xr[q];
        #pragma unroll
        for (int c = 0; c < C; ++c) {
            float4 wv = ((const float4*)Ws)[c * CH + q];   // wave-uniform -> LDS broadcast
            acc[c] += xv.x * wv.x + xv.y * wv.y + xv.z * wv.z + xv.w * wv.w;
        }
    }
    float4* zp = (float4*)(z + (long)node * C);
    #pragma unroll
    for (int q = 0; q < CQ; ++q)
        zp[q] = make_float4(acc[q*4+0], acc[q*4+1], acc[q*4+2], acc[q*4+3]);
}

// ---------- propagation hop (gather): zout[i] = dinv[i]^2*zin[i] + sum_e w*zin[col] ----------
__global__ void k_gather(const float* __restrict__ zin, const int* __restrict__ rowptr,
                         const int* __restrict__ col, const float* __restrict__ wgt,
                         const float* __restrict__ dinv, float* __restrict__ zout) {
    int t = blockIdx.x * blockDim.x + threadIdx.x;   // thread per (node, float4 chunk)
    if (t >= NN * CQ) return;
    int node = t >> 3;   // CQ = 8
    int q    = t & 7;
    float dn = dinv[node];
    float4 v = ((const float4*)zin)[node * CQ + q];
    float c  = dn * dn;
    float ax = c * v.x, ay = c * v.y, az = c * v.z, aw = c * v.w;
    int e0 = rowptr[node], e1 = rowptr[node + 1];
    for (int e = e0; e < e1; ++e) {
        int   s = col[e];
        float w = wgt[e];
        float4 u = ((const float4*)zin)[s * CQ + q];
        ax += w * u.x; ay += w * u.y; az += w * u.z; aw += w * u.w;
    }
    ((float4*)zout)[node * CQ + q] = make_float4(ax, ay, az, aw);
}

// ---------- epilogue: out = log_softmax(z + b) ----------
__global__ void k_finish(const float* __restrict__ z, const float* __restrict__ b,
                         float* __restrict__ out) {
    int node = blockIdx.x * blockDim.x + threadIdx.x;
    if (node >= NN) return;
    float v[C];
    const float4* zp = (const float4*)(z + (long)node * C);
    #pragma unroll
    for (int q = 0; q < CQ; ++q) {
        float4 t = zp[q];
        v[q*4+0] = t.x + b[q*4+0];
        v[q*4+1] = t.y + b[q*4+1];
        v[q*4+2] = t.z + b[q*4+2];
        v[q*4+3] = t.w + b[q*4+3];
    }
    float m = v[0];
    #pragma unroll
    for (int c = 1; c < C; ++c) m = fmaxf(m, v[c]);
    float s = 0.f;
    #pragma unroll
    for (int c = 0; c < C; ++c) s += expf(v[c] - m);
    float lse = m + logf(s);
    float4* op = (float4*)(out + (long)node * C);
    #pragma unroll
    for (int q = 0; q < CQ; ++q)
        op[q] = make_float4(v[q*4+0]-lse, v[q*4+1]-lse, v[q*4+2]-lse, v[q*4+3]-lse);
}

extern "C" void kernel_launch(void* const* d_in, const int* in_sizes, int n_in,
                              void* d_out, int out_size, void* d_ws, size_t ws_size,
                              hipStream_t stream) {
    const float* x  = (const float*)d_in[0];
    const int*   ei = (const int*)d_in[1];     // [2, NE] int32
    const float* W  = (const float*)d_in[2];
    const float* b  = (const float*)d_in[3];
    float* out = (float*)d_out;

    const int* srcA = ei;
    const int* dstA = ei + NE;

    // workspace layout (bytes, 256-aligned blocks)
    char* p = (char*)d_ws;
    auto alloc = [&](size_t bytes) { char* r = p; p += (bytes + 255) & ~(size_t)255; return r; };
    int*   cnt       = (int*)  alloc(sizeof(int) * NN);
    float* dinv      = (float*)alloc(sizeof(float) * NN);
    int*   rowptr    = (int*)  alloc(sizeof(int) * (NN + 1));
    int*   cursor    = (int*)  alloc(sizeof(int) * NN);
    int*   blocksums = (int*)  alloc(sizeof(int) * NB);
    int*   blockoff  = (int*)  alloc(sizeof(int) * NB);
    int*   col       = (int*)  alloc(sizeof(int) * NE);
    float* wgt       = (float*)alloc(sizeof(float) * NE);
    float* z0        = (float*)alloc(sizeof(float) * (size_t)NN * C);
    float* z1        = (float*)alloc(sizeof(float) * (size_t)NN * C);
    float* z2        = z0;   // hop2 writes back into z0 (only z1 is read then)

    // norm + CSR build
    k_zero    <<<(NN + 255) / 256, 256, 0, stream>>>(cnt);
    k_count   <<<(NE + 255) / 256, 256, 0, stream>>>(dstA, cnt);
    k_dinv    <<<(NN + 255) / 256, 256, 0, stream>>>(cnt, dinv);
    k_blocksum<<<NB, 256, 0, stream>>>(cnt, blocksums);
    k_scanB   <<<1, 512, 0, stream>>>(blocksums, blockoff, rowptr);
    k_scanC   <<<NB, 256, 0, stream>>>(cnt, blockoff, rowptr, cursor);
    k_fill    <<<(NE + 255) / 256, 256, 0, stream>>>(srcA, dstA, dinv, cursor, col, wgt);

    // project first (propagation commutes with the linear head)
    k_proj<<<(NN + 255) / 256, 256, 0, stream>>>(x, W, z0);

    // two hops on 32 features
    int gthreads = NN * CQ;
    k_gather<<<(gthreads + 255) / 256, 256, 0, stream>>>(z0, rowptr, col, wgt, dinv, z1);
    k_gather<<<(gthreads + 255) / 256, 256, 0, stream>>>(z1, rowptr, col, wgt, dinv, z2);

    // bias + log_softmax
    k_finish<<<(NN + 255) / 256, 256, 0, stream>>>(z2, b, out);
}